// Round 6
// baseline (124.682 us; speedup 1.0000x reference)
//
#include <hip/hip_runtime.h>
#include <hip/hip_fp16.h>

// SoftNCutsLoss via rank-2 separable factorization of the bilateral weight.
// w = exp(-(Iw-I0)^2/100)*wz(dz) ; exp(Iw*I0/50) ~= 1 + Iw*I0/50 (rel err <= 2e-4)
//  => w ~= g(I0)*g(Iw)*wz + [g(I0)*I0/50]*[g(Iw)*Iw]*wz,  g(u)=exp(-u^2/100)
// Pipeline (2 compute launches + tiny final):
//   passx : per (b,c) field pair: u_m = g*I^m*p, 9-wide box along x, half2 pack.
//   fused : per (xg, c, yseg) block: for each b, JOINT y-scan of U[b,c] and
//           U[b,4] (den), 3-tap z-comb via lane shuffles (z == lanes), multiply
//           by a_m(I_b) (shared I load + exp), sum over b into Sc/S4 register
//           accumulators, EPS-pad den fix; then contract with preds[b',c]
//           (each preds value serves BOTH num and den), block reduce,
//           replicated atomics.
//   final : 4 - sum_k (num+eps)/(den+eps)

constexpr int Pdim = 64;
constexpr int P3   = Pdim * Pdim * Pdim;   // 262144
constexpr int NREP = 16;

#define EPSF 2.2204460492503131e-16f

constexpr float WZ1   = 0.8290291181804004f;     // exp(-3/16)
constexpr float K2F   = 0.014426950408889634f;   // log2(e)/100
constexpr float C1F   = 0.02f;                   // 1/50
constexpr float WFULL = 81.0f * (1.0f + 2.0f * WZ1);

// ---------------------------------------------------------------------------
// Pass X: half2(U0,U1) = BoxX(g*p, g*I*p). thread = (y,z); scans 24 x, emits 16.
// Grid: (ygroup 16, pair 20, xseg 4), 256 thr (4 y-lines x 64 z-lanes).
// ---------------------------------------------------------------------------
__global__ __launch_bounds__(256)
void ncuts_passx(const float* __restrict__ batch, const float* __restrict__ preds,
                 __half2* __restrict__ U, float* __restrict__ acc) {
  const int t = threadIdx.x;
  if (blockIdx.x == 0 && blockIdx.y == 0 && blockIdx.z == 0) {
    acc[t] = 0.f; acc[t + 256] = 0.f;       // zero NREP*32 = 512 accumulators
  }
  const int z = t & 63, yh = t >> 6;
  const int y = blockIdx.x * 4 + yh;
  const int pair = blockIdx.y;              // b*5 + c; c=0..3 pred, c=4 den
  const int b = pair / 5, c = pair - 5 * b;
  const bool isden = (c == 4);
  const int X0 = 16 * (int)blockIdx.z - 4;
  const int lin = (y << 6) + z;
  const float* Ip = batch + b * P3 + lin;
  const float* Pp = isden ? Ip : preds + (b * 4 + c) * P3 + lin;
  __half2* Uo = U + pair * P3 + lin;

  float w0[9], w1[9];
#pragma unroll
  for (int i = 0; i < 9; ++i) { w0[i] = 0.f; w1[i] = 0.f; }
  float s0 = 0.f, s1 = 0.f;
#pragma unroll
  for (int i = 0; i < 24; ++i) {
    const int x = X0 + i;
    float u0 = 0.f, u1 = 0.f;
    if ((unsigned)x < 64u) {                // x uniform across block
      float I = Ip[x << 12];
      float g = exp2f(-I * I * K2F);
      float p = isden ? 1.f : Pp[x << 12];
      u0 = g * p;
      u1 = u0 * I;
    }
    const int r = i % 9;                    // static after full unroll
    s0 += u0 - w0[r]; w0[r] = u0;
    s1 += u1 - w1[r]; w1[r] = u1;
    if (i >= 8) Uo[(x - 4) << 12] = __floats2half2_rn(s0, s1);
  }
}

// ---------------------------------------------------------------------------
// Fused pass YZ + contraction. Grid: (xgroup 16, c 4, yseg 4), 256 thr
// (4 x-lines x 64 z-lanes). Each block: channel c, 16-y output range.
// ---------------------------------------------------------------------------
__global__ __launch_bounds__(256)
void ncuts_fused(const float* __restrict__ batch, const float* __restrict__ preds,
                 const __half2* __restrict__ U, float* __restrict__ acc) {
  __shared__ float redn[4][4], redd[4][4];
  const int t = threadIdx.x;
  const int z = t & 63, xh = t >> 6;
  const int x = blockIdx.x * 4 + xh;
  const int c = blockIdx.y;                 // 0..3 (den rides along)
  const int yo0 = 16 * (int)blockIdx.z;     // output y base
  const int Y0 = yo0 - 4;                   // scan ingest base
  const int xz = (x << 12) + z;

  const float cx = 9.f - (float)max(0, 4 - x) - (float)max(0, x - 59);
  const float cz = 1.f + WZ1 * ((z > 0 ? 1.f : 0.f) + (z < 63 ? 1.f : 0.f));

  float Sc[16], S4[16];
#pragma unroll
  for (int j = 0; j < 16; ++j) { Sc[j] = 0.f; S4[j] = 0.f; }

#pragma unroll 1
  for (int b = 0; b < 4; ++b) {
    const __half2* Un = U + (b * 5 + c) * P3 + xz;
    const __half2* Ud = U + (b * 5 + 4) * P3 + xz;
    const float*   Ip = batch + b * P3 + xz;
    float nw0[9], nw1[9], dw0[9], dw1[9];
#pragma unroll
    for (int i = 0; i < 9; ++i) { nw0[i] = 0.f; nw1[i] = 0.f; dw0[i] = 0.f; dw1[i] = 0.f; }
    float ns0 = 0.f, ns1 = 0.f, ds0 = 0.f, ds1 = 0.f;
#pragma unroll
    for (int i = 0; i < 24; ++i) {
      const int y = Y0 + i;
      float un0 = 0.f, un1 = 0.f, ud0 = 0.f, ud1 = 0.f;
      if ((unsigned)y < 64u) {
        float2 a = __half22float2(Un[y << 6]);
        float2 d = __half22float2(Ud[y << 6]);
        un0 = a.x; un1 = a.y; ud0 = d.x; ud1 = d.y;
      }
      const int r = i % 9;                  // static after full unroll
      ns0 += un0 - nw0[r]; nw0[r] = un0;
      ns1 += un1 - nw1[r]; nw1[r] = un1;
      ds0 += ud0 - dw0[r]; dw0[r] = ud0;
      ds1 += ud1 - dw1[r]; dw1[r] = ud1;
      if (i >= 8) {                         // i uniform: shuffles non-divergent
        const int yo = y - 4;
        float a0 = __shfl_up(ns0, 1, 64),   a1 = __shfl_up(ns1, 1, 64);
        float b0 = __shfl_down(ns0, 1, 64), b1 = __shfl_down(ns1, 1, 64);
        float e0 = __shfl_up(ds0, 1, 64),   e1 = __shfl_up(ds1, 1, 64);
        float f0 = __shfl_down(ds0, 1, 64), f1 = __shfl_down(ds1, 1, 64);
        if (z == 0)  { a0 = 0.f; a1 = 0.f; e0 = 0.f; e1 = 0.f; }
        if (z == 63) { b0 = 0.f; b1 = 0.f; f0 = 0.f; f1 = 0.f; }
        float vn0 = __builtin_fmaf(WZ1, a0 + b0, ns0);
        float vn1 = __builtin_fmaf(WZ1, a1 + b1, ns1);
        float vd0 = __builtin_fmaf(WZ1, e0 + f0, ds0);
        float vd1 = __builtin_fmaf(WZ1, e1 + f1, ds1);
        float I  = Ip[yo << 6];
        float g  = exp2f(-I * I * K2F);
        float gi = g * I * C1F;
        Sc[i - 8] += __builtin_fmaf(g, vn0, gi * vn1);
        float cy = 9.f - (float)max(0, 4 - yo) - (float)max(0, yo - 59);
        float corr = __builtin_fmaf(g, WFULL - cx * cy * cz, gi * vd1);
        S4[i - 8] += __builtin_fmaf(g, vd0, corr);
      }
    }
  }

  // ---- contraction: preds[b',c] serves both num (x Sc) and den (x S4) ----
  float pn[4] = {0.f, 0.f, 0.f, 0.f}, pd[4] = {0.f, 0.f, 0.f, 0.f};
#pragma unroll
  for (int b2 = 0; b2 < 4; ++b2) {
    const float* pp = preds + (b2 * 4 + c) * P3 + (x << 12) + (yo0 << 6) + z;
#pragma unroll
    for (int j = 0; j < 16; ++j) {
      float p = pp[j << 6];
      pn[b2] = __builtin_fmaf(p, Sc[j], pn[b2]);
      pd[b2] = __builtin_fmaf(p, S4[j], pd[b2]);
    }
  }

  // ---- reduce 8 values across the block ----
#pragma unroll
  for (int i = 0; i < 4; ++i) {
#pragma unroll
    for (int off = 32; off > 0; off >>= 1) {
      pn[i] += __shfl_down(pn[i], off, 64);
      pd[i] += __shfl_down(pd[i], off, 64);
    }
  }
  const int wave = t >> 6, lane = t & 63;
  if (lane == 0) {
#pragma unroll
    for (int i = 0; i < 4; ++i) { redn[wave][i] = pn[i]; redd[wave][i] = pd[i]; }
  }
  __syncthreads();
  if (t < 4) {                              // t = b'
    float n = redn[0][t] + redn[1][t] + redn[2][t] + redn[3][t];
    float d = redd[0][t] + redd[1][t] + redd[2][t] + redd[3][t];
    const int rep = ((int)blockIdx.x + 4 * (int)blockIdx.z) & (NREP - 1);
    atomicAdd(&acc[rep * 32 + t * 4 + c], n);
    atomicAdd(&acc[rep * 32 + 16 + t * 4 + c], d);
  }
}

__global__ void ncuts_final(const float* __restrict__ acc, float* __restrict__ out) {
  __shared__ float loss[16];
  int t = threadIdx.x;
  if (t < 16) {
    float n = 0.f, d = 0.f;
    for (int r = 0; r < NREP; ++r) { n += acc[r * 32 + t]; d += acc[r * 32 + 16 + t]; }
    loss[t] = (n + EPSF) / (d + EPSF);
  }
  __syncthreads();
  if (t < 4) {
    float s = loss[t * 4] + loss[t * 4 + 1] + loss[t * 4 + 2] + loss[t * 4 + 3];
    out[t] = 4.0f - s;
  }
}

// ===========================================================================
// Fallback (round-1 direct kernel) if the workspace is too small.
// ===========================================================================
constexpr int Rxy = 4;
constexpr int TXf = 8, TYf = 8;
constexpr int ZLEN = 2;
constexpr int RGX = 16, RGY = 16, RGZ = 10;
constexpr int YPf = 17, ZPf = 11;

__global__ __launch_bounds__(256, 2)
void ncuts_mainf(const float* __restrict__ batch, const float* __restrict__ preds,
                 float* __restrict__ acc) {
  __shared__ float  sB[RGX][YPf][ZPf];
  __shared__ float4 sP[RGX][YPf][ZPf];
  __shared__ float  red[4][32];

  const int t = threadIdx.x;
  const int tx = t & 7, ty = (t >> 3) & 7, tzt = t >> 6;
  const int bx0 = blockIdx.x * TXf, by0 = blockIdx.y * TYf, bz0 = blockIdx.z * 8;
  const int x = bx0 + tx, y = by0 + ty, z0 = bz0 + tzt * ZLEN;
  const int zc = tzt * ZLEN;

  float  den[ZLEN];
  float4 num[ZLEN];
#pragma unroll
  for (int j = 0; j < ZLEN; ++j) { den[j] = 0.f; num[j] = make_float4(0.f, 0.f, 0.f, 0.f); }

  const float C1 = -0.014426950408889634f;
  const float LWZ1 = -0.27050531991668065f;

  for (int b = 0; b < 4; ++b) {
    __syncthreads();
    for (int idx = t; idx < RGX * RGY * RGZ; idx += 256) {
      int rz = idx % RGZ, rq = idx / RGZ, ry = rq % RGY, rx = rq / RGY;
      int gx = bx0 + rx - Rxy, gy = by0 + ry - Rxy, gz = bz0 + rz - 1;
      bool in = ((unsigned)gx < 64u) & ((unsigned)gy < 64u) & ((unsigned)gz < 64u);
      float v = EPSF; float4 pv = make_float4(EPSF, EPSF, EPSF, EPSF);
      if (in) {
        int gi = (gx * Pdim + gy) * Pdim + gz;
        v = batch[b * P3 + gi];
        const float* pp = preds + b * 4 * P3 + gi;
        pv.x = pp[0]; pv.y = pp[P3]; pv.z = pp[2 * P3]; pv.w = pp[3 * P3];
      }
      sB[rx][ry][rz] = v; sP[rx][ry][rz] = pv;
    }
    __syncthreads();

    float I0[ZLEN];
#pragma unroll
    for (int j = 0; j < ZLEN; ++j) I0[j] = sB[tx + Rxy][ty + Rxy][zc + 1 + j];

#pragma unroll 1
    for (int dy = 0; dy < 9; ++dy) {
#pragma unroll 3
      for (int dx = 0; dx < 9; ++dx) {
        const float*  cb = &sB[tx + dx][ty + dy][zc];
        const float4* cp = &sP[tx + dx][ty + dy][zc];
        float colB[ZLEN + 2]; float4 colP[ZLEN + 2];
#pragma unroll
        for (int j = 0; j < ZLEN + 2; ++j) { colB[j] = cb[j]; colP[j] = cp[j]; }
#pragma unroll
        for (int j = 0; j < ZLEN; ++j) {
#pragma unroll
          for (int dz = 0; dz < 3; ++dz) {
            float d = colB[j + dz] - I0[j];
            float arg = __builtin_fmaf(d * d, C1, (dz == 1) ? 0.f : LWZ1);
            float w = exp2f(arg);
            den[j] += w;
            float4 p = colP[j + dz];
            num[j].x = __builtin_fmaf(w, p.x, num[j].x);
            num[j].y = __builtin_fmaf(w, p.y, num[j].y);
            num[j].z = __builtin_fmaf(w, p.z, num[j].z);
            num[j].w = __builtin_fmaf(w, p.w, num[j].w);
          }
        }
      }
    }
  }

  float pn[16], pd[16];
#pragma unroll
  for (int i = 0; i < 16; ++i) { pn[i] = 0.f; pd[i] = 0.f; }
#pragma unroll
  for (int b = 0; b < 4; ++b) {
#pragma unroll
    for (int j = 0; j < ZLEN; ++j) {
      const float* pp = preds + b * 4 * P3 + ((x * Pdim + y) * Pdim + z0 + j);
      float nsv[4] = {num[j].x, num[j].y, num[j].z, num[j].w};
#pragma unroll
      for (int k = 0; k < 4; ++k) {
        float pv = pp[k * P3];
        pn[b * 4 + k] = __builtin_fmaf(pv, nsv[k], pn[b * 4 + k]);
        pd[b * 4 + k] = __builtin_fmaf(pv, den[j], pd[b * 4 + k]);
      }
    }
  }
#pragma unroll
  for (int i = 0; i < 16; ++i) {
#pragma unroll
    for (int off = 32; off > 0; off >>= 1) {
      pn[i] += __shfl_down(pn[i], off, 64);
      pd[i] += __shfl_down(pd[i], off, 64);
    }
  }
  const int wave = t >> 6, lane = t & 63;
  if (lane == 0) {
#pragma unroll
    for (int i = 0; i < 16; ++i) { red[wave][i] = pn[i]; red[wave][16 + i] = pd[i]; }
  }
  __syncthreads();
  if (t < 32) {
    float s = red[0][t] + red[1][t] + red[2][t] + red[3][t];
    int bid = blockIdx.x + 8 * (blockIdx.y + 8 * (int)blockIdx.z);
    atomicAdd(&acc[(bid & (NREP - 1)) * 32 + t], s);
  }
}

__global__ void ncuts_zero(float* __restrict__ acc) {
  int t = threadIdx.x;
  if (t < NREP * 32) acc[t] = 0.f;
}

// ===========================================================================
extern "C" void kernel_launch(void* const* d_in, const int* in_sizes, int n_in,
                              void* d_out, int out_size, void* d_ws, size_t ws_size,
                              hipStream_t stream) {
  const float* batch = (const float*)d_in[0];
  const float* preds = (const float*)d_in[1];
  float* out = (float*)d_out;

  const size_t ub = (size_t)20 * P3 * sizeof(__half2);   // U: 20 MB
  const size_t need = ub + 8192;
  if (ws_size >= need) {
    char* base = (char*)d_ws;
    __half2* U   = (__half2*)(base + 256);
    float*   acc = (float*)(base + 512 + ub);            // 512 floats
    hipLaunchKernelGGL(ncuts_passx, dim3(16, 20, 4), dim3(256), 0, stream,
                       batch, preds, U, acc);
    hipLaunchKernelGGL(ncuts_fused, dim3(16, 4, 4), dim3(256), 0, stream,
                       batch, preds, U, acc);
    hipLaunchKernelGGL(ncuts_final, dim3(1), dim3(64), 0, stream, acc, out);
  } else {
    float* acc = (float*)d_ws;
    hipLaunchKernelGGL(ncuts_zero, dim3(1), dim3(512), 0, stream, acc);
    hipLaunchKernelGGL(ncuts_mainf, dim3(8, 8, 8), dim3(256), 0, stream,
                       batch, preds, acc);
    hipLaunchKernelGGL(ncuts_final, dim3(1), dim3(64), 0, stream, acc, out);
  }
}

// Round 7
// 100.092 us; speedup vs baseline: 1.2457x; 1.2457x over previous
//
#include <hip/hip_runtime.h>
#include <hip/hip_fp16.h>

// SoftNCutsLoss via rank-2 separable factorization of the bilateral weight.
// w = exp(-(Iw-I0)^2/100)*wz(dz) ; exp(Iw*I0/50) ~= 1 + Iw*I0/50 (rel err <= 2e-4)
//  => w ~= g(I0)*g(Iw)*wz + [g(I0)*I0/50]*[g(Iw)*Iw]*wz,  g(u)=exp(-u^2/100)
// Pipeline (2 compute launches + tiny final):
//   passx : per (b,c) field pair: u_m = g*I^m*p, 9-wide box along x, half2 pack.
//           (R3's proven 640-block / 2-xseg config.)
//   fused : per (xg, c, yseg, bhalf) block: for its TWO b's, JOINT y-scan of
//           U[b,c] and U[b,4], 3-tap z-comb via lane shuffles (z == lanes),
//           multiply by a_m(I_b), accumulate partial Sc/S4[8]; contract with
//           preds[b',c] for all 4 b' (linear in b => atomics sum partials).
//           1024 blocks = 16 waves/CU (R6 starved at 4).
//   final : 4 - sum_k (num+eps)/(den+eps)

constexpr int Pdim = 64;
constexpr int P3   = Pdim * Pdim * Pdim;   // 262144
constexpr int NREP = 16;

#define EPSF 2.2204460492503131e-16f

constexpr float WZ1   = 0.8290291181804004f;     // exp(-3/16)
constexpr float K2F   = 0.014426950408889634f;   // log2(e)/100
constexpr float C1F   = 0.02f;                   // 1/50
constexpr float WFULL = 81.0f * (1.0f + 2.0f * WZ1);

// ---------------------------------------------------------------------------
// Pass X: half2(U0,U1) = BoxX(g*p, g*I*p). thread = (y,z); 2 x-segments.
// Grid: (ygroup 16, pair 20, xseg 2), 256 thr (4 y-lines x 64 z-lanes).
// ---------------------------------------------------------------------------
template<int X0, int NX, int FIRSTW>
__device__ __forceinline__ void passx_body(const float* __restrict__ Ip,
                                           const float* __restrict__ Pp,
                                           __half2* __restrict__ Uo,
                                           bool isden) {
  float w0[9], w1[9];
#pragma unroll
  for (int i = 0; i < 9; ++i) { w0[i] = 0.f; w1[i] = 0.f; }
  float s0 = 0.f, s1 = 0.f;
#pragma unroll
  for (int i = 0; i < NX; ++i) {
    const int x = X0 + i;
    float u0 = 0.f, u1 = 0.f;
    if (x < 64) {                           // zero-pad outside
      float I = Ip[x << 12];
      float g = exp2f(-I * I * K2F);
      float p = isden ? 1.f : Pp[x << 12];
      u0 = g * p;
      u1 = u0 * I;
    }
    const int r = i % 9;                    // static after full unroll
    s0 += u0 - w0[r]; w0[r] = u0;
    s1 += u1 - w1[r]; w1[r] = u1;
    if (i >= FIRSTW) Uo[(x - 4) << 12] = __floats2half2_rn(s0, s1);
  }
}

__global__ __launch_bounds__(256)
void ncuts_passx(const float* __restrict__ batch, const float* __restrict__ preds,
                 __half2* __restrict__ U, float* __restrict__ acc) {
  const int t = threadIdx.x;
  if (blockIdx.x == 0 && blockIdx.y == 0 && blockIdx.z == 0) {
    acc[t] = 0.f; acc[t + 256] = 0.f;       // zero NREP*32 = 512 accumulators
  }
  const int z = t & 63, yh = t >> 6;
  const int y = blockIdx.x * 4 + yh;
  const int pair = blockIdx.y;              // b*5 + c; c=0..3 pred, c=4 den
  const int b = pair / 5, c = pair - 5 * b;
  const bool isden = (c == 4);
  const int lin = (y << 6) + z;
  const float* Ip = batch + b * P3 + lin;
  const float* Pp = isden ? Ip : preds + (b * 4 + c) * P3 + lin;
  __half2* Uo = U + pair * P3 + lin;
  if (blockIdx.z == 0) passx_body< 0, 36, 4>(Ip, Pp, Uo, isden);  // out x 0..31
  else                 passx_body<28, 40, 8>(Ip, Pp, Uo, isden);  // out x 32..63
}

// ---------------------------------------------------------------------------
// Fused pass YZ + contraction. Grid: (xgroup 16, c 4, yseg 8 | bh 2) = 1024
// blocks, 256 thr (4 x-lines x 64 z-lanes). Each block: channel c, 8-y output
// range, TWO b's. Partial Sc/S4 contracted with all 4 preds b'.
// ---------------------------------------------------------------------------
__global__ __launch_bounds__(256)
void ncuts_fused(const float* __restrict__ batch, const float* __restrict__ preds,
                 const __half2* __restrict__ U, float* __restrict__ acc) {
  __shared__ float redn[4][4], redd[4][4];
  const int t = threadIdx.x;
  const int z = t & 63, xh = t >> 6;
  const int x = blockIdx.x * 4 + xh;
  const int c = blockIdx.y;                 // 0..3 (den rides along)
  const int zc_ = blockIdx.z;
  const int yseg = zc_ & 7, bh = zc_ >> 3;  // yseg 0..7, b-half 0..1
  const int yo0 = 8 * yseg;                 // output y base (8 outputs)
  const int Y0 = yo0 - 4;                   // ingest base (16 ingests)
  const int xz = (x << 12) + z;

  const float cx = 9.f - (float)max(0, 4 - x) - (float)max(0, x - 59);
  const float cz = 1.f + WZ1 * ((z > 0 ? 1.f : 0.f) + (z < 63 ? 1.f : 0.f));

  float Sc[8], S4[8];
#pragma unroll
  for (int j = 0; j < 8; ++j) { Sc[j] = 0.f; S4[j] = 0.f; }

#pragma unroll 1
  for (int ib = 0; ib < 2; ++ib) {
    const int b = bh * 2 + ib;
    const __half2* Un = U + (b * 5 + c) * P3 + xz;
    const __half2* Ud = U + (b * 5 + 4) * P3 + xz;
    const float*   Ip = batch + b * P3 + xz;
    float nw0[9], nw1[9], dw0[9], dw1[9];
#pragma unroll
    for (int i = 0; i < 9; ++i) { nw0[i] = 0.f; nw1[i] = 0.f; dw0[i] = 0.f; dw1[i] = 0.f; }
    float ns0 = 0.f, ns1 = 0.f, ds0 = 0.f, ds1 = 0.f;
#pragma unroll
    for (int i = 0; i < 16; ++i) {
      const int y = Y0 + i;
      float un0 = 0.f, un1 = 0.f, ud0 = 0.f, ud1 = 0.f;
      if ((unsigned)y < 64u) {
        float2 a = __half22float2(Un[y << 6]);
        float2 d = __half22float2(Ud[y << 6]);
        un0 = a.x; un1 = a.y; ud0 = d.x; ud1 = d.y;
      }
      const int r = i % 9;                  // static after full unroll
      ns0 += un0 - nw0[r]; nw0[r] = un0;
      ns1 += un1 - nw1[r]; nw1[r] = un1;
      ds0 += ud0 - dw0[r]; dw0[r] = ud0;
      ds1 += ud1 - dw1[r]; dw1[r] = ud1;
      if (i >= 8) {                         // i uniform: shuffles non-divergent
        const int yo = y - 4;
        float a0 = __shfl_up(ns0, 1, 64),   a1 = __shfl_up(ns1, 1, 64);
        float b0 = __shfl_down(ns0, 1, 64), b1 = __shfl_down(ns1, 1, 64);
        float e0 = __shfl_up(ds0, 1, 64),   e1 = __shfl_up(ds1, 1, 64);
        float f0 = __shfl_down(ds0, 1, 64), f1 = __shfl_down(ds1, 1, 64);
        if (z == 0)  { a0 = 0.f; a1 = 0.f; e0 = 0.f; e1 = 0.f; }
        if (z == 63) { b0 = 0.f; b1 = 0.f; f0 = 0.f; f1 = 0.f; }
        float vn0 = __builtin_fmaf(WZ1, a0 + b0, ns0);
        float vn1 = __builtin_fmaf(WZ1, a1 + b1, ns1);
        float vd0 = __builtin_fmaf(WZ1, e0 + f0, ds0);
        float vd1 = __builtin_fmaf(WZ1, e1 + f1, ds1);
        float I  = Ip[yo << 6];
        float g  = exp2f(-I * I * K2F);
        float gi = g * I * C1F;
        Sc[i - 8] += __builtin_fmaf(g, vn0, gi * vn1);
        float cy = 9.f - (float)max(0, 4 - yo) - (float)max(0, yo - 59);
        float corr = __builtin_fmaf(g, WFULL - cx * cy * cz, gi * vd1);
        S4[i - 8] += __builtin_fmaf(g, vd0, corr);
      }
    }
  }

  // ---- contraction: preds[b',c] serves both num (x Sc) and den (x S4) ----
  float pn[4] = {0.f, 0.f, 0.f, 0.f}, pd[4] = {0.f, 0.f, 0.f, 0.f};
#pragma unroll
  for (int b2 = 0; b2 < 4; ++b2) {
    const float* pp = preds + (b2 * 4 + c) * P3 + (x << 12) + (yo0 << 6) + z;
#pragma unroll
    for (int j = 0; j < 8; ++j) {
      float p = pp[j << 6];
      pn[b2] = __builtin_fmaf(p, Sc[j], pn[b2]);
      pd[b2] = __builtin_fmaf(p, S4[j], pd[b2]);
    }
  }

  // ---- reduce 8 values across the block ----
#pragma unroll
  for (int i = 0; i < 4; ++i) {
#pragma unroll
    for (int off = 32; off > 0; off >>= 1) {
      pn[i] += __shfl_down(pn[i], off, 64);
      pd[i] += __shfl_down(pd[i], off, 64);
    }
  }
  const int wave = t >> 6, lane = t & 63;
  if (lane == 0) {
#pragma unroll
    for (int i = 0; i < 4; ++i) { redn[wave][i] = pn[i]; redd[wave][i] = pd[i]; }
  }
  __syncthreads();
  if (t < 4) {                              // t = b'
    float n = redn[0][t] + redn[1][t] + redn[2][t] + redn[3][t];
    float d = redd[0][t] + redd[1][t] + redd[2][t] + redd[3][t];
    const int rep = ((int)blockIdx.x + (int)blockIdx.z) & (NREP - 1);
    atomicAdd(&acc[rep * 32 + t * 4 + c], n);
    atomicAdd(&acc[rep * 32 + 16 + t * 4 + c], d);
  }
}

__global__ void ncuts_final(const float* __restrict__ acc, float* __restrict__ out) {
  __shared__ float loss[16];
  int t = threadIdx.x;
  if (t < 16) {
    float n = 0.f, d = 0.f;
    for (int r = 0; r < NREP; ++r) { n += acc[r * 32 + t]; d += acc[r * 32 + 16 + t]; }
    loss[t] = (n + EPSF) / (d + EPSF);
  }
  __syncthreads();
  if (t < 4) {
    float s = loss[t * 4] + loss[t * 4 + 1] + loss[t * 4 + 2] + loss[t * 4 + 3];
    out[t] = 4.0f - s;
  }
}

// ===========================================================================
// Fallback (round-1 direct kernel) if the workspace is too small.
// ===========================================================================
constexpr int Rxy = 4;
constexpr int TXf = 8, TYf = 8;
constexpr int ZLEN = 2;
constexpr int RGX = 16, RGY = 16, RGZ = 10;
constexpr int YPf = 17, ZPf = 11;

__global__ __launch_bounds__(256, 2)
void ncuts_mainf(const float* __restrict__ batch, const float* __restrict__ preds,
                 float* __restrict__ acc) {
  __shared__ float  sB[RGX][YPf][ZPf];
  __shared__ float4 sP[RGX][YPf][ZPf];
  __shared__ float  red[4][32];

  const int t = threadIdx.x;
  const int tx = t & 7, ty = (t >> 3) & 7, tzt = t >> 6;
  const int bx0 = blockIdx.x * TXf, by0 = blockIdx.y * TYf, bz0 = blockIdx.z * 8;
  const int x = bx0 + tx, y = by0 + ty, z0 = bz0 + tzt * ZLEN;
  const int zc = tzt * ZLEN;

  float  den[ZLEN];
  float4 num[ZLEN];
#pragma unroll
  for (int j = 0; j < ZLEN; ++j) { den[j] = 0.f; num[j] = make_float4(0.f, 0.f, 0.f, 0.f); }

  const float C1 = -0.014426950408889634f;
  const float LWZ1 = -0.27050531991668065f;

  for (int b = 0; b < 4; ++b) {
    __syncthreads();
    for (int idx = t; idx < RGX * RGY * RGZ; idx += 256) {
      int rz = idx % RGZ, rq = idx / RGZ, ry = rq % RGY, rx = rq / RGY;
      int gx = bx0 + rx - Rxy, gy = by0 + ry - Rxy, gz = bz0 + rz - 1;
      bool in = ((unsigned)gx < 64u) & ((unsigned)gy < 64u) & ((unsigned)gz < 64u);
      float v = EPSF; float4 pv = make_float4(EPSF, EPSF, EPSF, EPSF);
      if (in) {
        int gi = (gx * Pdim + gy) * Pdim + gz;
        v = batch[b * P3 + gi];
        const float* pp = preds + b * 4 * P3 + gi;
        pv.x = pp[0]; pv.y = pp[P3]; pv.z = pp[2 * P3]; pv.w = pp[3 * P3];
      }
      sB[rx][ry][rz] = v; sP[rx][ry][rz] = pv;
    }
    __syncthreads();

    float I0[ZLEN];
#pragma unroll
    for (int j = 0; j < ZLEN; ++j) I0[j] = sB[tx + Rxy][ty + Rxy][zc + 1 + j];

#pragma unroll 1
    for (int dy = 0; dy < 9; ++dy) {
#pragma unroll 3
      for (int dx = 0; dx < 9; ++dx) {
        const float*  cb = &sB[tx + dx][ty + dy][zc];
        const float4* cp = &sP[tx + dx][ty + dy][zc];
        float colB[ZLEN + 2]; float4 colP[ZLEN + 2];
#pragma unroll
        for (int j = 0; j < ZLEN + 2; ++j) { colB[j] = cb[j]; colP[j] = cp[j]; }
#pragma unroll
        for (int j = 0; j < ZLEN; ++j) {
#pragma unroll
          for (int dz = 0; dz < 3; ++dz) {
            float d = colB[j + dz] - I0[j];
            float arg = __builtin_fmaf(d * d, C1, (dz == 1) ? 0.f : LWZ1);
            float w = exp2f(arg);
            den[j] += w;
            float4 p = colP[j + dz];
            num[j].x = __builtin_fmaf(w, p.x, num[j].x);
            num[j].y = __builtin_fmaf(w, p.y, num[j].y);
            num[j].z = __builtin_fmaf(w, p.z, num[j].z);
            num[j].w = __builtin_fmaf(w, p.w, num[j].w);
          }
        }
      }
    }
  }

  float pn[16], pd[16];
#pragma unroll
  for (int i = 0; i < 16; ++i) { pn[i] = 0.f; pd[i] = 0.f; }
#pragma unroll
  for (int b = 0; b < 4; ++b) {
#pragma unroll
    for (int j = 0; j < ZLEN; ++j) {
      const float* pp = preds + b * 4 * P3 + ((x * Pdim + y) * Pdim + z0 + j);
      float nsv[4] = {num[j].x, num[j].y, num[j].z, num[j].w};
#pragma unroll
      for (int k = 0; k < 4; ++k) {
        float pv = pp[k * P3];
        pn[b * 4 + k] = __builtin_fmaf(pv, nsv[k], pn[b * 4 + k]);
        pd[b * 4 + k] = __builtin_fmaf(pv, den[j], pd[b * 4 + k]);
      }
    }
  }
#pragma unroll
  for (int i = 0; i < 16; ++i) {
#pragma unroll
    for (int off = 32; off > 0; off >>= 1) {
      pn[i] += __shfl_down(pn[i], off, 64);
      pd[i] += __shfl_down(pd[i], off, 64);
    }
  }
  const int wave = t >> 6, lane = t & 63;
  if (lane == 0) {
#pragma unroll
    for (int i = 0; i < 16; ++i) { red[wave][i] = pn[i]; red[wave][16 + i] = pd[i]; }
  }
  __syncthreads();
  if (t < 32) {
    float s = red[0][t] + red[1][t] + red[2][t] + red[3][t];
    int bid = blockIdx.x + 8 * (blockIdx.y + 8 * (int)blockIdx.z);
    atomicAdd(&acc[(bid & (NREP - 1)) * 32 + t], s);
  }
}

__global__ void ncuts_zero(float* __restrict__ acc) {
  int t = threadIdx.x;
  if (t < NREP * 32) acc[t] = 0.f;
}

// ===========================================================================
extern "C" void kernel_launch(void* const* d_in, const int* in_sizes, int n_in,
                              void* d_out, int out_size, void* d_ws, size_t ws_size,
                              hipStream_t stream) {
  const float* batch = (const float*)d_in[0];
  const float* preds = (const float*)d_in[1];
  float* out = (float*)d_out;

  const size_t ub = (size_t)20 * P3 * sizeof(__half2);   // U: 20 MB
  const size_t need = ub + 8192;
  if (ws_size >= need) {
    char* base = (char*)d_ws;
    __half2* U   = (__half2*)(base + 256);
    float*   acc = (float*)(base + 512 + ub);            // 512 floats
    hipLaunchKernelGGL(ncuts_passx, dim3(16, 20, 2), dim3(256), 0, stream,
                       batch, preds, U, acc);
    hipLaunchKernelGGL(ncuts_fused, dim3(16, 4, 16), dim3(256), 0, stream,
                       batch, preds, U, acc);
    hipLaunchKernelGGL(ncuts_final, dim3(1), dim3(64), 0, stream, acc, out);
  } else {
    float* acc = (float*)d_ws;
    hipLaunchKernelGGL(ncuts_zero, dim3(1), dim3(512), 0, stream, acc);
    hipLaunchKernelGGL(ncuts_mainf, dim3(8, 8, 8), dim3(256), 0, stream,
                       batch, preds, acc);
    hipLaunchKernelGGL(ncuts_final, dim3(1), dim3(64), 0, stream, acc, out);
  }
}

// Round 8
// 98.849 us; speedup vs baseline: 1.2613x; 1.0126x over previous
//
#include <hip/hip_runtime.h>
#include <hip/hip_fp16.h>

// SoftNCutsLoss via rank-2 separable factorization of the bilateral weight.
// w = exp(-(Iw-I0)^2/100)*wz(dz) ; exp(Iw*I0/50) ~= 1 + Iw*I0/50 (rel err <= 2e-4)
//  => w ~= g(I0)*g(Iw)*wz + [g(I0)*I0/50]*[g(Iw)*Iw]*wz,  g(u)=exp(-u^2/100)
// Pipeline (R3 structure, 4-seg scans for 2x TLP):
//   passx   : per (b,c): u_m = g*I^m*p, 9-wide box along x, half2 pack.
//             4 x-segments -> 1280 blocks = 20 waves/CU.
//   passyz  : 9-wide box along y + 3-tap z-comb via lane shuffles (z==lanes).
//             4 y-segments -> 1280 blocks.
//   contract: rank-2 recombine + EPS-pad den fix + fused einsums + block
//             reduce + replicated atomics (R3 scalar 2-iteration version).
//   final   : 4 - sum_k (num+eps)/(den+eps)

constexpr int Pdim = 64;
constexpr int P3   = Pdim * Pdim * Pdim;   // 262144
constexpr int NREP = 16;

#define EPSF 2.2204460492503131e-16f

constexpr float WZ1   = 0.8290291181804004f;     // exp(-3/16)
constexpr float K2F   = 0.014426950408889634f;   // log2(e)/100
constexpr float C1F   = 0.02f;                   // 1/50
constexpr float WFULL = 81.0f * (1.0f + 2.0f * WZ1);

// ---------------------------------------------------------------------------
// Pass X: half2(U0,U1) = BoxX(g*p, g*I*p). thread = (y,z); scans 24 x, emits 16.
// Grid: (ygroup 16, pair 20, xseg 4), 256 thr (4 y-lines x 64 z-lanes).
// ---------------------------------------------------------------------------
__global__ __launch_bounds__(256)
void ncuts_passx(const float* __restrict__ batch, const float* __restrict__ preds,
                 __half2* __restrict__ U, float* __restrict__ acc) {
  const int t = threadIdx.x;
  if (blockIdx.x == 0 && blockIdx.y == 0 && blockIdx.z == 0) {
    acc[t] = 0.f; acc[t + 256] = 0.f;       // zero NREP*32 = 512 accumulators
  }
  const int z = t & 63, yh = t >> 6;
  const int y = blockIdx.x * 4 + yh;
  const int pair = blockIdx.y;              // b*5 + c; c=0..3 pred, c=4 den
  const int b = pair / 5, c = pair - 5 * b;
  const bool isden = (c == 4);
  const int X0 = 16 * (int)blockIdx.z - 4;
  const int lin = (y << 6) + z;
  const float* Ip = batch + b * P3 + lin;
  const float* Pp = isden ? Ip : preds + (b * 4 + c) * P3 + lin;
  __half2* Uo = U + pair * P3 + lin;

  float w0[9], w1[9];
#pragma unroll
  for (int i = 0; i < 9; ++i) { w0[i] = 0.f; w1[i] = 0.f; }
  float s0 = 0.f, s1 = 0.f;
#pragma unroll
  for (int i = 0; i < 24; ++i) {
    const int x = X0 + i;
    float u0 = 0.f, u1 = 0.f;
    if ((unsigned)x < 64u) {                // x uniform across block
      float I = Ip[x << 12];
      float g = exp2f(-I * I * K2F);
      float p = isden ? 1.f : Pp[x << 12];
      u0 = g * p;
      u1 = u0 * I;
    }
    const int r = i % 9;                    // static after full unroll
    s0 += u0 - w0[r]; w0[r] = u0;
    s1 += u1 - w1[r]; w1[r] = u1;
    if (i >= 8) Uo[(x - 4) << 12] = __floats2half2_rn(s0, s1);
  }
}

// ---------------------------------------------------------------------------
// Pass YZ: 9-wide y box (registers) + 3-tap z-comb via shuffles (z = lane).
// Grid: (xgroup 16, pair 20, yseg 4), 256 thr (4 x x 64 z). Scan 24 y, emit 16.
// ---------------------------------------------------------------------------
__global__ __launch_bounds__(256)
void ncuts_passyz(const __half2* __restrict__ U, __half2* __restrict__ V) {
  const int t = threadIdx.x;
  const int z = t & 63, xh = t >> 6;
  const int x = blockIdx.x * 4 + xh;
  const int pair = blockIdx.y;
  const int Y0 = 16 * (int)blockIdx.z - 4;
  const __half2* src = U + pair * P3 + (x << 12) + z;
  __half2* dst = V + pair * P3 + (x << 12) + z;

  float w0[9], w1[9];
#pragma unroll
  for (int i = 0; i < 9; ++i) { w0[i] = 0.f; w1[i] = 0.f; }
  float s0 = 0.f, s1 = 0.f;
#pragma unroll
  for (int i = 0; i < 24; ++i) {
    const int y = Y0 + i;
    float u0 = 0.f, u1 = 0.f;
    if ((unsigned)y < 64u) {
      float2 u = __half22float2(src[y << 6]);
      u0 = u.x; u1 = u.y;
    }
    const int r = i % 9;
    s0 += u0 - w0[r]; w0[r] = u0;
    s1 += u1 - w1[r]; w1[r] = u1;
    if (i >= 8) {                           // i uniform: shuffles non-divergent
      float up0 = __shfl_up(s0, 1, 64),   up1 = __shfl_up(s1, 1, 64);
      float dn0 = __shfl_down(s0, 1, 64), dn1 = __shfl_down(s1, 1, 64);
      if (z == 0)  { up0 = 0.f; up1 = 0.f; }   // volume edge == wave edge
      if (z == 63) { dn0 = 0.f; dn1 = 0.f; }
      float v0 = __builtin_fmaf(WZ1, up0 + dn0, s0);
      float v1 = __builtin_fmaf(WZ1, up1 + dn1, s1);
      dst[(y - 4) << 6] = __floats2half2_rn(v0, v1);
    }
  }
}

// ---------------------------------------------------------------------------
// Contract: rank-2 recombine, den boundary fix, fused einsums, block reduce.
// Grid: 512 blocks x 256 thr, 2 voxels per thread (R3's proven version).
// ---------------------------------------------------------------------------
__global__ __launch_bounds__(256)
void ncuts_contract(const float* __restrict__ batch, const float* __restrict__ preds,
                    const __half2* __restrict__ V, float* __restrict__ acc) {
  __shared__ float red[4][32];
  const int t = threadIdx.x;
  float pn[16], pd[16];
#pragma unroll
  for (int i = 0; i < 16; ++i) { pn[i] = 0.f; pd[i] = 0.f; }

#pragma unroll 1
  for (int it = 0; it < 2; ++it) {
    const int v = blockIdx.x * 512 + it * 256 + t;
    const int z = v & 63, y = (v >> 6) & 63, x = v >> 12;

    float a0[4], a1[4], gsum = 0.f;
#pragma unroll
    for (int b = 0; b < 4; ++b) {
      float I = batch[b * P3 + v];
      float g = exp2f(-I * I * K2F);
      a0[b] = g; a1[b] = g * I * C1F; gsum += g;
    }

    float ns[4] = {0.f, 0.f, 0.f, 0.f};
    float ds = 0.f;
#pragma unroll
    for (int b = 0; b < 4; ++b) {
#pragma unroll
      for (int c = 0; c < 5; ++c) {
        float2 u = __half22float2(V[(b * 5 + c) * P3 + v]);
        float zc = __builtin_fmaf(a0[b], u.x, a1[b] * u.y);
        if (c < 4) ns[c] += zc;
        else       ds    += zc;
      }
    }
    // den boundary correction: out-of-bounds image cells have w ~= g(I0)*wz(dz)
    float cx = (float)(9 - max(0, 4 - x) - max(0, x - 59));
    float cy = (float)(9 - max(0, 4 - y) - max(0, y - 59));
    float cz = 1.f + WZ1 * (float)((int)(z > 0) + (int)(z < 63));
    ds = __builtin_fmaf(gsum, WFULL - cx * cy * cz, ds);

#pragma unroll
    for (int b = 0; b < 4; ++b) {
#pragma unroll
      for (int k = 0; k < 4; ++k) {
        float p = preds[(b * 4 + k) * P3 + v];
        pn[b * 4 + k] = __builtin_fmaf(p, ns[k], pn[b * 4 + k]);
        pd[b * 4 + k] = __builtin_fmaf(p, ds,    pd[b * 4 + k]);
      }
    }
  }

#pragma unroll
  for (int i = 0; i < 16; ++i) {
#pragma unroll
    for (int off = 32; off > 0; off >>= 1) {
      pn[i] += __shfl_down(pn[i], off, 64);
      pd[i] += __shfl_down(pd[i], off, 64);
    }
  }
  const int wave = t >> 6, lane = t & 63;
  if (lane == 0) {
#pragma unroll
    for (int i = 0; i < 16; ++i) { red[wave][i] = pn[i]; red[wave][16 + i] = pd[i]; }
  }
  __syncthreads();
  if (t < 32) {
    float s = red[0][t] + red[1][t] + red[2][t] + red[3][t];
    atomicAdd(&acc[(blockIdx.x & (NREP - 1)) * 32 + t], s);
  }
}

__global__ void ncuts_final(const float* __restrict__ acc, float* __restrict__ out) {
  __shared__ float loss[16];
  int t = threadIdx.x;
  if (t < 16) {
    float n = 0.f, d = 0.f;
    for (int r = 0; r < NREP; ++r) { n += acc[r * 32 + t]; d += acc[r * 32 + 16 + t]; }
    loss[t] = (n + EPSF) / (d + EPSF);
  }
  __syncthreads();
  if (t < 4) {
    float s = loss[t * 4] + loss[t * 4 + 1] + loss[t * 4 + 2] + loss[t * 4 + 3];
    out[t] = 4.0f - s;
  }
}

// ===========================================================================
// Fallback (round-1 direct kernel) if the workspace is too small.
// ===========================================================================
constexpr int Rxy = 4;
constexpr int TXf = 8, TYf = 8;
constexpr int ZLEN = 2;
constexpr int RGX = 16, RGY = 16, RGZ = 10;
constexpr int YPf = 17, ZPf = 11;

__global__ __launch_bounds__(256, 2)
void ncuts_mainf(const float* __restrict__ batch, const float* __restrict__ preds,
                 float* __restrict__ acc) {
  __shared__ float  sB[RGX][YPf][ZPf];
  __shared__ float4 sP[RGX][YPf][ZPf];
  __shared__ float  red[4][32];

  const int t = threadIdx.x;
  const int tx = t & 7, ty = (t >> 3) & 7, tzt = t >> 6;
  const int bx0 = blockIdx.x * TXf, by0 = blockIdx.y * TYf, bz0 = blockIdx.z * 8;
  const int x = bx0 + tx, y = by0 + ty, z0 = bz0 + tzt * ZLEN;
  const int zc = tzt * ZLEN;

  float  den[ZLEN];
  float4 num[ZLEN];
#pragma unroll
  for (int j = 0; j < ZLEN; ++j) { den[j] = 0.f; num[j] = make_float4(0.f, 0.f, 0.f, 0.f); }

  const float C1 = -0.014426950408889634f;
  const float LWZ1 = -0.27050531991668065f;

  for (int b = 0; b < 4; ++b) {
    __syncthreads();
    for (int idx = t; idx < RGX * RGY * RGZ; idx += 256) {
      int rz = idx % RGZ, rq = idx / RGZ, ry = rq % RGY, rx = rq / RGY;
      int gx = bx0 + rx - Rxy, gy = by0 + ry - Rxy, gz = bz0 + rz - 1;
      bool in = ((unsigned)gx < 64u) & ((unsigned)gy < 64u) & ((unsigned)gz < 64u);
      float v = EPSF; float4 pv = make_float4(EPSF, EPSF, EPSF, EPSF);
      if (in) {
        int gi = (gx * Pdim + gy) * Pdim + gz;
        v = batch[b * P3 + gi];
        const float* pp = preds + b * 4 * P3 + gi;
        pv.x = pp[0]; pv.y = pp[P3]; pv.z = pp[2 * P3]; pv.w = pp[3 * P3];
      }
      sB[rx][ry][rz] = v; sP[rx][ry][rz] = pv;
    }
    __syncthreads();

    float I0[ZLEN];
#pragma unroll
    for (int j = 0; j < ZLEN; ++j) I0[j] = sB[tx + Rxy][ty + Rxy][zc + 1 + j];

#pragma unroll 1
    for (int dy = 0; dy < 9; ++dy) {
#pragma unroll 3
      for (int dx = 0; dx < 9; ++dx) {
        const float*  cb = &sB[tx + dx][ty + dy][zc];
        const float4* cp = &sP[tx + dx][ty + dy][zc];
        float colB[ZLEN + 2]; float4 colP[ZLEN + 2];
#pragma unroll
        for (int j = 0; j < ZLEN + 2; ++j) { colB[j] = cb[j]; colP[j] = cp[j]; }
#pragma unroll
        for (int j = 0; j < ZLEN; ++j) {
#pragma unroll
          for (int dz = 0; dz < 3; ++dz) {
            float d = colB[j + dz] - I0[j];
            float arg = __builtin_fmaf(d * d, C1, (dz == 1) ? 0.f : LWZ1);
            float w = exp2f(arg);
            den[j] += w;
            float4 p = colP[j + dz];
            num[j].x = __builtin_fmaf(w, p.x, num[j].x);
            num[j].y = __builtin_fmaf(w, p.y, num[j].y);
            num[j].z = __builtin_fmaf(w, p.z, num[j].z);
            num[j].w = __builtin_fmaf(w, p.w, num[j].w);
          }
        }
      }
    }
  }

  float pn[16], pd[16];
#pragma unroll
  for (int i = 0; i < 16; ++i) { pn[i] = 0.f; pd[i] = 0.f; }
#pragma unroll
  for (int b = 0; b < 4; ++b) {
#pragma unroll
    for (int j = 0; j < ZLEN; ++j) {
      const float* pp = preds + b * 4 * P3 + ((x * Pdim + y) * Pdim + z0 + j);
      float nsv[4] = {num[j].x, num[j].y, num[j].z, num[j].w};
#pragma unroll
      for (int k = 0; k < 4; ++k) {
        float pv = pp[k * P3];
        pn[b * 4 + k] = __builtin_fmaf(pv, nsv[k], pn[b * 4 + k]);
        pd[b * 4 + k] = __builtin_fmaf(pv, den[j], pd[b * 4 + k]);
      }
    }
  }
#pragma unroll
  for (int i = 0; i < 16; ++i) {
#pragma unroll
    for (int off = 32; off > 0; off >>= 1) {
      pn[i] += __shfl_down(pn[i], off, 64);
      pd[i] += __shfl_down(pd[i], off, 64);
    }
  }
  const int wave = t >> 6, lane = t & 63;
  if (lane == 0) {
#pragma unroll
    for (int i = 0; i < 16; ++i) { red[wave][i] = pn[i]; red[wave][16 + i] = pd[i]; }
  }
  __syncthreads();
  if (t < 32) {
    float s = red[0][t] + red[1][t] + red[2][t] + red[3][t];
    int bid = blockIdx.x + 8 * (blockIdx.y + 8 * (int)blockIdx.z);
    atomicAdd(&acc[(bid & (NREP - 1)) * 32 + t], s);
  }
}

__global__ void ncuts_zero(float* __restrict__ acc) {
  int t = threadIdx.x;
  if (t < NREP * 32) acc[t] = 0.f;
}

// ===========================================================================
extern "C" void kernel_launch(void* const* d_in, const int* in_sizes, int n_in,
                              void* d_out, int out_size, void* d_ws, size_t ws_size,
                              hipStream_t stream) {
  const float* batch = (const float*)d_in[0];
  const float* preds = (const float*)d_in[1];
  float* out = (float*)d_out;

  const size_t ub = (size_t)20 * P3 * sizeof(__half2);   // U: 20 MB
  const size_t vb = ub;                                  // V: 20 MB
  const size_t need = ub + vb + 8192;
  if (ws_size >= need) {
    char* base = (char*)d_ws;
    __half2* U   = (__half2*)(base + 256);
    __half2* V   = (__half2*)(base + 256 + ub);
    float*   acc = (float*)(base + 512 + ub + vb);       // 512 floats
    hipLaunchKernelGGL(ncuts_passx, dim3(16, 20, 4), dim3(256), 0, stream,
                       batch, preds, U, acc);
    hipLaunchKernelGGL(ncuts_passyz, dim3(16, 20, 4), dim3(256), 0, stream, U, V);
    hipLaunchKernelGGL(ncuts_contract, dim3(512), dim3(256), 0, stream,
                       batch, preds, V, acc);
    hipLaunchKernelGGL(ncuts_final, dim3(1), dim3(64), 0, stream, acc, out);
  } else {
    float* acc = (float*)d_ws;
    hipLaunchKernelGGL(ncuts_zero, dim3(1), dim3(512), 0, stream, acc);
    hipLaunchKernelGGL(ncuts_mainf, dim3(8, 8, 8), dim3(256), 0, stream,
                       batch, preds, acc);
    hipLaunchKernelGGL(ncuts_final, dim3(1), dim3(64), 0, stream, acc, out);
  }
}